// Round 1
// baseline (110.602 us; speedup 1.0000x reference)
//
#include <hip/hip_runtime.h>
#include <hip/hip_bf16.h>

#define D 512
#define NWAY 64
#define KSHOT 16
#define NQ 8192

typedef __bf16 bf16_t;
typedef __bf16 bf16x8_t __attribute__((ext_vector_type(8)));
typedef __bf16 bf16x4_t __attribute__((ext_vector_type(4)));
typedef float  f32x4    __attribute__((ext_vector_type(4)));

typedef __attribute__((address_space(1))) const void gv_t;
typedef __attribute__((address_space(3))) void lv_t;
__device__ __forceinline__ void ld16(const void* g, void* l) {
    __builtin_amdgcn_global_load_lds((gv_t*)g, (lv_t*)l, 16, 0, 0);
}

// Bsw: [ck(8)][n(576)][seg(8)] bf16, off = ck*36864 + n*64 + ((s^(n&7))*8)
//   rows 0..511 = W (bf16), rows 512..575 = G_c = W^T p_c

// ---------------------------------------------------------------- K_PREP1
// b<256: P[c][jq*128..+128] = cm_c . W_j + b_j  (cm recomputed per block, cheap)
// b>=256 (128 blocks): W -> bf16 swizzled into Bsw rows 0..511
__global__ __launch_bounds__(256) void k_prep1(
    const float* __restrict__ sup, const float* __restrict__ W,
    const float* __restrict__ bias, float* __restrict__ Pg,
    bf16_t* __restrict__ Bsw)
{
    const int b = blockIdx.x, t = threadIdx.x;

    if (b < 256) {                         // ---- P blocks
        const int c = b >> 2, jq = b & 3;
        __shared__ __align__(16) float cm[D];
        {   // cm_c = mean over shots (float2 per thread)
            const int d = t * 2;
            float sx = 0.f, sy = 0.f;
#pragma unroll
            for (int j = 0; j < KSHOT; ++j) {
                float2 v = *(const float2*)(sup + (size_t)(c * KSHOT + j) * D + d);
                sx += v.x; sy += v.y;
            }
            cm[d] = sx * (1.0f / KSHOT); cm[d + 1] = sy * (1.0f / KSHOT);
        }
        __syncthreads();
        // P: 128 j per block, each j split over 2 lanes (256-dim half-dots)
        const int j = jq * 128 + (t >> 1);
        const int half = t & 1;
        const f32x4* wr = (const f32x4*)(W + (size_t)j * D + half * 256);
        const f32x4* cr = (const f32x4*)(cm + half * 256);
        float s = 0.f;
#pragma unroll 8
        for (int i = 0; i < 64; ++i) {
            f32x4 a = cr[i], wv = wr[i];
            s += a[0]*wv[0] + a[1]*wv[1] + a[2]*wv[2] + a[3]*wv[3];
        }
        s += __shfl_xor(s, 1);
        if (!half) Pg[(size_t)c * D + j] = s + bias[j];
        return;
    }

    {                                      // ---- W conversion, 4 rows/block
        const int n = (b - 256) * 4 + (t >> 6);
        const int sl = t & 63;
        const f32x4* wp = (const f32x4*)(W + (size_t)n * D + sl * 8);
        f32x4 v0 = wp[0], v1 = wp[1];
        bf16x8_t hv = { (bf16_t)v0[0], (bf16_t)v0[1], (bf16_t)v0[2], (bf16_t)v0[3],
                        (bf16_t)v1[0], (bf16_t)v1[1], (bf16_t)v1[2], (bf16_t)v1[3] };
        const int ck = sl >> 3, s = sl & 7;
        *(bf16x8_t*)(Bsw + (size_t)ck * 36864 + n * 64 + ((s ^ (n & 7)) * 8)) = hv;
    }
}

// ---------------------------------------------------------------- K_PREP2
// 256 blocks: G_c[kq*128..+128] -> Bsw rows 512+c (swizzled bf16);
// kq==0 blocks also reduce ph_c = ||p||^2 - 2 b.p
__global__ __launch_bounds__(256) void k_prep2(
    const float* __restrict__ Pg, const float* __restrict__ W,
    const float* __restrict__ bias, bf16_t* __restrict__ Bsw,
    float* __restrict__ ph)
{
    __shared__ __align__(16) float Pl[D];
    __shared__ float sG[2][128];
    __shared__ float red[4];

    const int c = blockIdx.x >> 2, kc = blockIdx.x & 3;
    const int t = threadIdx.x;
    const int kl = t & 127, jh = t >> 7;
    const int k = kc * 128 + kl;

    ((float2*)Pl)[t] = ((const float2*)(Pg + (size_t)c * D))[t];
    __syncthreads();

    float g = 0.f;
    const float* wcol = W + (size_t)jh * 256 * D + k;
#pragma unroll 8
    for (int j = 0; j < 256; ++j)
        g += Pl[jh * 256 + j] * wcol[(size_t)j * D];
    sG[jh][kl] = g;

    if (kc == 0) {
        float v1 = Pl[t], v2 = Pl[t + 256];
        float pp = v1 * v1 - 2.0f * bias[t] * v1 + v2 * v2 - 2.0f * bias[t + 256] * v2;
#pragma unroll
        for (int off = 32; off; off >>= 1) pp += __shfl_xor(pp, off);
        if ((t & 63) == 0) red[t >> 6] = pp;
    }
    __syncthreads();

    if (jh == 0) {
        const float gt = sG[0][kl] + sG[1][kl];
        const int n = 512 + c;
        const int ck = k >> 6, s = (k >> 3) & 7, e = k & 7;
        Bsw[(size_t)ck * 36864 + n * 64 + ((s ^ (c & 7)) * 8) + e] = (bf16_t)gt;
    }
    if (kc == 0 && t == 0) ph[c] = red[0] + red[1] + red[2] + red[3];
}

// ---------------------------------------------------------------- K_MAIN
// 256 blocks x 512 thr, 1 block/CU. Double-buffered LDS pipeline (T3-lite):
// per chunk: issue next chunk's 9 global_load_lds (B) + ds_write (A from
// preloaded regs) -> compute current chunk -> single __syncthreads().
// vmcnt(0)/lgkmcnt(0) drain lands AFTER compute, so the 72 KB L2 DMA
// overlaps the 18 MFMAs. A (query tile) is preloaded ONCE to registers as
// bf16, removing the per-chunk HBM-latency stall from the critical path.
__global__ __launch_bounds__(512, 2) void k_main(
    const float* __restrict__ query, const bf16_t* __restrict__ Bsw,
    const float* __restrict__ bias, const float* __restrict__ ph,
    float* __restrict__ out)
{
    __shared__ bf16_t Bb[2][36864]; // 147,456 B
    __shared__ bf16_t Ab[2][2048];  //   8,192 B
    __shared__ float qln[4][32];    //     512 B
    __shared__ float phs[NWAY];     //     256 B
    __shared__ float bs[576];       //   2,304 B   (total 158,720 B -> 1 block/CU)

    const int t = threadIdx.x, bm = blockIdx.x;
    bs[t] = bias[t];
    if (t < NWAY) { bs[512 + t] = 0.f; phs[t] = ph[t]; }

    const int l = t & 63, w = t >> 6;
    const int wm = w & 1, wn = w >> 1;
    const int r15 = l & 15, quad = l >> 4;

    const int xt0 = ((quad ^ (r15 & 7)) * 8);
    const int xt1 = (((4 + quad) ^ (r15 & 7)) * 8);
    const int aoff = (wm * 16 + r15) * 64;
    const int boff = (wn * 144 + r15) * 64;
    const int wb = w * 4608 + l * 8;

    // ---- A preload: each thread owns row am, 4 cols per chunk, all 8 chunks
    const int am = t >> 4;                 // 0..31
    const int ac4 = t & 15;                // 4-col group within a 64-col chunk
    const int a_lds = am * 64 + (((ac4 >> 1) ^ (am & 7)) * 8) + (ac4 & 1) * 4;
    const float* aqp = query + (size_t)(bm * 32 + am) * D + ac4 * 4;

    bf16x4_t areg[8];
#pragma unroll
    for (int ck = 0; ck < 8; ++ck) {
        f32x4 v = *(const f32x4*)(aqp + ck * 64);
        areg[ck] = (bf16x4_t){ (bf16_t)v[0], (bf16_t)v[1], (bf16_t)v[2], (bf16_t)v[3] };
    }

    f32x4 acc[9];
#pragma unroll
    for (int i = 0; i < 9; ++i) acc[i] = (f32x4){0.f, 0.f, 0.f, 0.f};

    // ---- prologue: stage chunk 0 into buffer 0
    {
#pragma unroll
        for (int i = 0; i < 9; ++i)
            ld16(Bsw + wb + i * 512, &Bb[0][wb + i * 512]);
        *(bf16x4_t*)(&Ab[0][a_lds]) = areg[0];
    }
    __syncthreads();   // drains vmcnt(0)+lgkmcnt(0): chunk 0 ready

    // ---- main loop: issue-next / compute-current / one barrier per chunk
#pragma unroll
    for (int ck = 0; ck < 8; ++ck) {
        const int cur = ck & 1;
        if (ck < 7) {
            const int nxt = cur ^ 1;
            const size_t sb = (size_t)(ck + 1) * 36864;
#pragma unroll
            for (int i = 0; i < 9; ++i)
                ld16(Bsw + sb + wb + i * 512, &Bb[nxt][wb + i * 512]);
            *(bf16x4_t*)(&Ab[nxt][a_lds]) = areg[ck + 1];
        }

        bf16x8_t a0 = *(const bf16x8_t*)(&Ab[cur][aoff + xt0]);
        bf16x8_t a1 = *(const bf16x8_t*)(&Ab[cur][aoff + xt1]);
#pragma unroll
        for (int tt = 0; tt < 9; ++tt) {
            bf16x8_t b0 = *(const bf16x8_t*)(&Bb[cur][boff + tt * 1024 + xt0]);
            bf16x8_t b1 = *(const bf16x8_t*)(&Bb[cur][boff + tt * 1024 + xt1]);
            acc[tt] = __builtin_amdgcn_mfma_f32_16x16x32_bf16(a0, b0, acc[tt], 0, 0, 0);
            acc[tt] = __builtin_amdgcn_mfma_f32_16x16x32_bf16(a1, b1, acc[tt], 0, 0, 0);
        }

        if (ck < 7) __syncthreads();   // next chunk staged + WAR guard
    }

    // ---- qn = sum over W-cols of (e + bias)^2 ; constant bound, masked ----
    float qp[4] = {0.f, 0.f, 0.f, 0.f};
#pragma unroll
    for (int tt = 0; tt < 9; ++tt) {
        const int colbase = wn * 144 + tt * 16;
        const float m = (colbase < 512) ? 1.f : 0.f;   // wave-uniform
        const float bv = bs[colbase + r15];
#pragma unroll
        for (int reg = 0; reg < 4; ++reg) {
            float v = acc[tt][reg] + bv;
            qp[reg] += m * v * v;
        }
    }
#pragma unroll
    for (int reg = 0; reg < 4; ++reg) {
        float s = qp[reg];
        s += __shfl_xor(s, 1); s += __shfl_xor(s, 2);
        s += __shfl_xor(s, 4); s += __shfl_xor(s, 8);
        if (r15 == 0) qln[wn][wm * 16 + quad * 4 + reg] = s;
    }
    __syncthreads();

    // ---- wn==3 waves write dists: qt + ph[c] - 2 * (q.G_c) ----
    if (wn == 3) {
#pragma unroll
        for (int reg = 0; reg < 4; ++reg) {
            const int row_local = quad * 4 + reg;
            const float qt = qln[0][wm * 16 + row_local] + qln[1][wm * 16 + row_local] +
                             qln[2][wm * 16 + row_local] + qln[3][wm * 16 + row_local];
            const int rowg = bm * 32 + wm * 16 + row_local;
#pragma unroll
            for (int tg = 0; tg < 4; ++tg) {
                const int c = tg * 16 + r15;
                out[(size_t)rowg * NWAY + c] = qt + phs[c] - 2.0f * acc[5 + tg][reg];
            }
        }
    }
}

// ---------------------------------------------------------------- launch
extern "C" void kernel_launch(void* const* d_in, const int* in_sizes, int n_in,
                              void* d_out, int out_size, void* d_ws, size_t ws_size,
                              hipStream_t stream)
{
    const float* support = (const float*)d_in[0];
    const float* query   = (const float*)d_in[1];
    const float* W       = (const float*)d_in[2];
    const float* bias    = (const float*)d_in[3];
    float* out = (float*)d_out;

    char* ws = (char*)d_ws;
    bf16_t* Bsw = (bf16_t*)ws;                    // 589,824 B
    float*  ph  = (float*)(ws + 589824);          //     256 B
    float*  Pg  = (float*)(ws + 589824 + 256);    // 131,072 B

    k_prep1<<<384, 256, 0, stream>>>(support, W, bias, Pg, Bsw);
    k_prep2<<<256, 256, 0, stream>>>(Pg, W, bias, Bsw, ph);
    k_main<<<256, 512, 0, stream>>>(query, Bsw, bias, ph, out);
}